// Round 6
// baseline (504.845 us; speedup 1.0000x reference)
//
#include <hip/hip_runtime.h>
#include <hip/hip_bf16.h>

#define M_TOT 400
#define M_SHOT 100
#define KD 49152
#define DDIM 512
#define KCODE 512

using f16x8  = __attribute__((ext_vector_type(8))) _Float16;
using f32x16 = __attribute__((ext_vector_type(16))) float;

// ---------------- K1: encoder GEMM via f16-limb MFMA, single pass ----------------
// zA = sum xh*wh ; zB = sum (xh*wl + xl*wh)   with wh,wl limbs of 1024*w
// z_e = 2^-10 * zA + 2^-21 * zB
__global__ __launch_bounds__(256, 2)
void k1_gemm(const float* __restrict__ xs, const float* __restrict__ xq,
             const float* __restrict__ W,
             float* __restrict__ zA, float* __restrict__ zB) {
    __shared__ _Float16 Wh[64][64];   // [n][k ^ (n&56)]  XOR-swizzled
    __shared__ _Float16 Wl[64][64];
    const int tid  = threadIdx.x;
    const int lane = tid & 63;
    const int wid  = tid >> 6;
    const int widm = wid >> 1;      // 0..1 : m 32-block within 64-row tile
    const int widn = wid & 1;       // 0..1 : n 32-block

    const int b   = blockIdx.x;     // 0..1023
    const int xcd = b & 7;
    const int jj  = b >> 3;         // 0..127
    const int ks  = xcd * 8 + (jj & 7);   // 0..63
    const int nt  = (jj >> 3) & 7;        // 0..7
    const int mh  = jj >> 6;              // 0..1
    const int kbase  = ks * 768;
    const int ntbase = nt * 64;

    const int l31    = lane & 31;
    const int khalf  = lane >> 5;   // 0/1
    const int nloc   = widn * 32 + l31;
    const int colswz = nloc & 56;

    f32x16 accA[4] = {};
    f32x16 accB[4] = {};

    for (int ks2 = 0; ks2 < 12; ks2++) {
        const int krow0 = kbase + ks2 * 64;
        // stage W[krow0..+64][ntbase..+64], limb-split, transposed + swizzled
        #pragma unroll
        for (int it = 0; it < 4; it++) {
            int t  = tid + 256 * it;     // 0..1023
            int kk = t >> 4;             // 0..63
            int n0 = (t & 15) << 2;      // 0..60 (4-aligned, within one octet)
            float4 v = *(const float4*)(W + (size_t)(krow0 + kk) * DDIM + ntbase + n0);
            int col = kk ^ (n0 & 56);
            float vv[4] = {v.x, v.y, v.z, v.w};
            #pragma unroll
            for (int q = 0; q < 4; q++) {
                float wsc = vv[q] * 1024.0f;
                _Float16 h = (_Float16)wsc;
                Wh[n0 + q][col] = h;
                Wl[n0 + q][col] = (_Float16)((wsc - (float)h) * 2048.0f);
            }
        }
        __syncthreads();

        #pragma unroll
        for (int k16 = 0; k16 < 4; k16++) {
            const int kof  = k16 * 16 + khalf * 8;
            const int colb = kof ^ colswz;
            f16x8 bh = *(const f16x8*)&Wh[nloc][colb];
            f16x8 bl = *(const f16x8*)&Wl[nloc][colb];
            const int aoff = krow0 + kof;
            #pragma unroll
            for (int mt = 0; mt < 4; mt++) {
                const int mbase = mh * 256 + mt * 64 + widm * 32;
                if (mbase >= M_TOT) continue;            // wave-uniform skip
                const int mrow = mbase + l31;
                f16x8 ah = {};
                f16x8 al = {};
                if (mrow < M_TOT) {
                    const float* xrow = (mrow < M_SHOT) ? xs + (size_t)mrow * KD
                                                        : xq + (size_t)(mrow - M_SHOT) * KD;
                    float4 v0 = *(const float4*)(xrow + aoff);
                    float4 v1 = *(const float4*)(xrow + aoff + 4);
                    float vv[8] = {v0.x, v0.y, v0.z, v0.w, v1.x, v1.y, v1.z, v1.w};
                    #pragma unroll
                    for (int q = 0; q < 8; q++) {
                        _Float16 h = (_Float16)vv[q];
                        ah[q] = h;
                        al[q] = (_Float16)((vv[q] - (float)h) * 2048.0f);
                    }
                }
                accA[mt] = __builtin_amdgcn_mfma_f32_32x32x16_f16(ah, bh, accA[mt], 0, 0, 0);
                accB[mt] = __builtin_amdgcn_mfma_f32_32x32x16_f16(ah, bl, accB[mt], 0, 0, 0);
                accB[mt] = __builtin_amdgcn_mfma_f32_32x32x16_f16(al, bh, accB[mt], 0, 0, 0);
            }
        }
        __syncthreads();
    }

    // epilogue: C/D layout col=lane&31, row=(r&3)+8*(r>>2)+4*(lane>>5)
    const int ncol = ntbase + widn * 32 + l31;
    #pragma unroll
    for (int mt = 0; mt < 4; mt++) {
        const int mb = mh * 256 + mt * 64 + widm * 32;
        if (mb >= M_TOT) continue;
        #pragma unroll
        for (int r = 0; r < 16; r++) {
            int mrow = mb + ((r & 3) + 8 * (r >> 2) + 4 * khalf);
            if (mrow < M_TOT) {
                atomicAdd(&zA[(size_t)mrow * DDIM + ncol], accA[mt][r]);
                atomicAdd(&zB[(size_t)mrow * DDIM + ncol], accB[mt][r]);
            }
        }
    }
}

// ---------------- K2: distances + argmin (fp32, limb-combine + bias, cnorm inline) ------
__global__ __launch_bounds__(256) void k2_argmin(const float* __restrict__ zA,
                                                 const float* __restrict__ zB,
                                                 const float* __restrict__ bias,
                                                 const float* __restrict__ cb,
                                                 int* __restrict__ idxOut) {
    __shared__ float zsh[4][512];
    __shared__ float rv[4][256];
    __shared__ int   ri[4][256];
    const int tid = threadIdx.x;
    const int m0  = blockIdx.x * 4;

    for (int i = tid; i < 4 * 512; i += 256) {
        int r = i >> 9, d = i & 511;
        size_t o = (size_t)(m0 + r) * DDIM + d;
        zsh[r][d] = zA[o] * 0x1p-10f + zB[o] * 0x1p-21f + bias[d];
    }
    __syncthreads();

    float acc0[4] = {0, 0, 0, 0}, acc1[4] = {0, 0, 0, 0};
    float cn0 = 0.0f, cn1 = 0.0f;
    const int k0 = tid * 2;
    for (int d = 0; d < 512; d++) {
        float2 cp = *(const float2*)(cb + (size_t)d * KCODE + k0);
        cn0 += cp.x * cp.x; cn1 += cp.y * cp.y;
        #pragma unroll
        for (int r = 0; r < 4; r++) {
            float z = zsh[r][d];
            acc0[r] += z * cp.x;
            acc1[r] += z * cp.y;
        }
    }

    for (int r = 0; r < 4; r++) {
        float v0 = cn0 - 2.0f * acc0[r];
        float v1 = cn1 - 2.0f * acc1[r];
        bool t = (v1 < v0);
        rv[r][tid] = t ? v1 : v0;
        ri[r][tid] = t ? (k0 + 1) : k0;
    }
    __syncthreads();
    for (int s = 128; s > 0; s >>= 1) {
        if (tid < s) {
            for (int r = 0; r < 4; r++) {
                float v2 = rv[r][tid + s]; int i2 = ri[r][tid + s];
                float v1 = rv[r][tid];     int i1 = ri[r][tid];
                if (v2 < v1 || (v2 == v1 && i2 < i1)) { rv[r][tid] = v2; ri[r][tid] = i2; }
            }
        }
        __syncthreads();
    }
    if (tid < 4) idxOut[m0 + tid] = ri[tid][0];
}

// ---------------- K3: prototypes (mean over 5 shots, normalized) ----------------
__global__ __launch_bounds__(256) void k3_proto(const int* __restrict__ idx,
                                                const float* __restrict__ cb,
                                                float* __restrict__ proton) {
    const int bw  = blockIdx.x;   // 0..19 = b*5+w
    const int tid = threadIdx.x;
    __shared__ float red[256];
    __shared__ int   sid[5];
    if (tid < 5) sid[tid] = idx[bw * 5 + tid];
    __syncthreads();
    float p[2];
    #pragma unroll
    for (int j = 0; j < 2; j++) {
        int d = tid + j * 256;
        float s = 0.0f;
        for (int ss = 0; ss < 5; ss++) s += cb[(size_t)d * KCODE + sid[ss]];
        p[j] = s * 0.2f;
    }
    red[tid] = p[0] * p[0] + p[1] * p[1];
    __syncthreads();
    for (int s = 128; s > 0; s >>= 1) {
        if (tid < s) red[tid] += red[tid + s];
        __syncthreads();
    }
    float rn = rsqrtf(red[0]);
    proton[(size_t)bw * 512 + tid]       = p[0] * rn;
    proton[(size_t)bw * 512 + tid + 256] = p[1] * rn;
}

// ---------------- K4: query normalize + cosine logits (f32 OUTPUT) ----------------
__global__ __launch_bounds__(256) void k4_logits(const int* __restrict__ idx,
                                                 const float* __restrict__ cb,
                                                 const float* __restrict__ proton,
                                                 const float* __restrict__ tempp,
                                                 float* __restrict__ out) {
    const int n  = blockIdx.x;    // 0..299
    const int bq = n / 75;
    const int tid = threadIdx.x;
    __shared__ float red[256];
    const int i = idx[M_SHOT + n];
    float q0 = cb[(size_t)tid * KCODE + i];
    float q1 = cb[(size_t)(tid + 256) * KCODE + i];

    float vals[6];
    vals[0] = q0 * q0 + q1 * q1;
    for (int w = 0; w < 5; w++) {
        const float* pw = proton + (size_t)(bq * 5 + w) * 512;
        vals[1 + w] = q0 * pw[tid] + q1 * pw[tid + 256];
    }
    float res[6];
    for (int j = 0; j < 6; j++) {
        red[tid] = vals[j];
        __syncthreads();
        for (int s = 128; s > 0; s >>= 1) {
            if (tid < s) red[tid] += red[tid + s];
            __syncthreads();
        }
        res[j] = red[0];
        __syncthreads();
    }
    if (tid == 0) {
        float temp = tempp[0];
        float rn = rsqrtf(res[0]);
        for (int w = 0; w < 5; w++)
            out[n * 5 + w] = temp * rn * res[1 + w];
    }
}

static const void* find_by_size(void* const* d_in, const int* in_sizes, int n_in,
                                long elems) {
    for (int i = 0; i < n_in; i++) {
        long s = in_sizes[i];
        if (s == elems || s == elems * 4) return d_in[i];   // elements or f32 bytes
    }
    return nullptr;
}

extern "C" void kernel_launch(void* const* d_in, const int* in_sizes, int n_in,
                              void* d_out, int out_size, void* d_ws, size_t ws_size,
                              hipStream_t stream) {
    const float* xs   = (const float*)find_by_size(d_in, in_sizes, n_in, 4915200L);
    const float* xq   = (const float*)find_by_size(d_in, in_sizes, n_in, 14745600L);
    const float* W    = (const float*)find_by_size(d_in, in_sizes, n_in, 25165824L);
    const float* bias = (const float*)find_by_size(d_in, in_sizes, n_in, 512L);
    const float* cb   = (const float*)find_by_size(d_in, in_sizes, n_in, 262144L);
    const float* temp = (const float*)find_by_size(d_in, in_sizes, n_in, 1L);
    if (!xs || !xq || !W || !bias || !cb || !temp) {
        xs = (const float*)d_in[0]; xq = (const float*)d_in[1];
        W  = (const float*)d_in[2]; bias = (const float*)d_in[3];
        cb = (const float*)d_in[4]; temp = (const float*)d_in[5];
    }
    float* out = (float*)d_out;   // reference output dtype is float32

    float* zA     = (float*)d_ws;             // 204800 f32
    float* zB     = zA + 204800;              // 204800 f32
    int*   idx    = (int*)(zB + 204800);      // 400 i32
    float* proton = (float*)(idx + 400);      // 10240 f32

    hipMemsetAsync(zA, 0, (size_t)409600 * sizeof(float), stream);
    k1_gemm<<<1024, 256, 0, stream>>>(xs, xq, W, zA, zB);
    k2_argmin<<<100, 256, 0, stream>>>(zA, zB, bias, cb, idx);
    k3_proto<<<20, 256, 0, stream>>>(idx, cb, proton);
    k4_logits<<<300, 256, 0, stream>>>(idx, cb, proton, temp, out);
}